// Round 15
// baseline (210.985 us; speedup 1.0000x reference)
//
#include <hip/hip_runtime.h>

#define N_PTS 1000000
#define H_DIM 200
#define W_DIM 70400
#define FILL_V -9999999.0f

// ws layout (R13-verified): counts[W int] | wpack[6656 bf16] | feat[1M u32] | list4[W][maxk] u32
#define COUNTS_BYTES ((size_t)W_DIM * sizeof(int))
#define WPACK_ELEMS  6656
#define WPACK_BYTES  ((size_t)WPACK_ELEMS * 2)
#define FEAT_BYTES   ((size_t)N_PTS * 4)

typedef __attribute__((ext_vector_type(4))) float f32x4;
typedef __attribute__((ext_vector_type(8))) short bf16x8;

__device__ __forceinline__ unsigned bperm_u(unsigned src_lane, unsigned v) {
    return (unsigned)__builtin_amdgcn_ds_bpermute((int)(src_lane << 2), (int)v);
}
__device__ __forceinline__ unsigned cvt_pk_bf16(float lo, float hi) {
    unsigned d;
    asm("v_cvt_pk_bf16_f32 %0, %1, %2" : "=v"(d) : "v"(lo), "v"(hi));
    return d;
}
__device__ __forceinline__ bf16x8 mk_frag(unsigned d0, unsigned d1,
                                          unsigned d2, unsigned d3) {
    union { unsigned u[4]; bf16x8 s; } u;
    u.u[0] = d0; u.u[1] = d1; u.u[2] = d2; u.u[3] = d3;
    return u.s;
}

// ---------------------------------------------------------------------------
// Prep (unchanged from R11, verified): A2 kappa'd, A1/A3/A4 linear.
// ---------------------------------------------------------------------------
__global__ void __launch_bounds__(256) pack_weights_kernel(
    const float* __restrict__ w1, const float* __restrict__ b1,
    const float* __restrict__ w2, const float* __restrict__ b2,
    const float* __restrict__ w3, const float* __restrict__ b3,
    const float* __restrict__ w4, const float* __restrict__ b4,
    unsigned short* __restrict__ wp)
{
    for (int idx = threadIdx.x; idx < WPACK_ELEMS; idx += 256) {
        const int rem  = idx & 511;
        const int lane = rem >> 3, j = rem & 7;
        const int c16 = lane & 15, gk = lane >> 4;
        const int kloc = gk * 8 + j;
        float v = 0.0f;
        if (idx < 1024) {                       // A1: linear
            const int row = (idx >> 9) * 16 + c16, k = kloc;
            if (row < 18) v = (k < 4) ? w1[row * 4 + k] : (k == 4 ? b1[row] : 0.0f);
        } else if (idx < 2560) {                // A2: KAPPA (R11-verified)
            const int row = ((idx - 1024) >> 9) * 16 + c16;
            const int f = (j < 4) ? (4 * gk + j) : (16 + 4 * gk + (j - 4));
            if (row < 36) v = (f < 18) ? w2[row * 18 + f] : (f == 18 ? b2[row] : 0.0f);
        } else if (idx < 5632) {                // A3: linear
            const int f = (idx - 2560) >> 9;
            const int row = (f >> 1) * 16 + c16, k = (f & 1) * 32 + kloc;
            if (row < 36) v = (k < 36) ? w3[row * 36 + k] : (k == 36 ? b3[row] : 0.0f);
        } else {                                // A4: linear
            const int row = c16, k = ((idx - 5632) >> 9) * 32 + kloc;
            if (row == 0) v = (k < 36) ? w4[k] : (k == 36 ? b4[0] : 0.0f);
        }
        const unsigned b = __float_as_uint(v);  // f32 -> bf16 RNE
        wp[idx] = (unsigned short)((b + 0x7FFFu + ((b >> 16) & 1u)) >> 16);
    }
}

// ---------------------------------------------------------------------------
// Kernel S (R15): scatter bookkeeping ONLY -- tindex read, atomicAdd,
// 4B key store. Needs NOTHING from the MLP (key = (i<<8)|row).
// R14 post-mortem: WRITE_SIZE ~63-65MB has been invariant through entry
// width (8B->4B), XCD partitioning, and store hoisting -- the only constant
// is the 1M device-scope atomicAdds (~64B RMW at the coherent point = 64MB).
// This kernel gives the atomics a pure-memory regime: 524K threads, ~2 pts
// each, thousands of independent chains -> latency fully TLP-hidden, and
// the cost becomes SEPARATELY MEASURABLE (the discriminating experiment).
// Slot ordering within a column is irrelevant: dedup uses the key.
// ---------------------------------------------------------------------------
__global__ void __launch_bounds__(256) slot_kernel(
    const int* __restrict__ tindex,
    int* __restrict__ counts,
    unsigned* __restrict__ list4,
    int maxk)
{
    if (tindex[0] == -1) return;            // empty-branch: no scatter at all
    const int step = gridDim.x * 256;
    for (int i = blockIdx.x * 256 + threadIdx.x; i < N_PTS; i += step) {
        const int2 hw = ((const int2*)tindex)[i];   // (row, col)
        const int pos = atomicAdd(&counts[hw.y], 1);
        if (pos < maxk)
            list4[(size_t)hw.y * maxk + pos] = ((unsigned)i << 8) | (unsigned)hw.x;
    }
}

// ---------------------------------------------------------------------------
// Kernel A v12 (R15): R11-verified MFMA body, scatter AMPUTATED.
// No tindex (beyond empty check), no atomicAdd, no scattered store -- the
// only output is the coalesced feat[i] stream (4MB). If the atomic/scatter
// was the wall, this kernel approaches its issue bound (~25-35us predicted,
// VALUBusy up ~2x, WRITE_SIZE ~5MB).
// ---------------------------------------------------------------------------
__global__ void __launch_bounds__(256) mlp_feat_kernel(
    const float* __restrict__ input,        // [4][N]
    const int* __restrict__ tindex,         // empty-branch check only
    const unsigned short* __restrict__ wp,  // packed bf16 fragments
    unsigned* __restrict__ feat)            // [N] value bits, linear
{
    if (tindex[0] == -1) return;            // empty-branch

    const int l   = threadIdx.x & 63;
    const int wav = (blockIdx.x * 256 + threadIdx.x) >> 6;
    const int base = wav << 6;
    if (base >= N_PTS) return;              // whole-wave early out (N%64==0)
    const int i = base + l;
    const int c16 = l & 15, g = l >> 4;

    const bf16x8* __restrict__ wf = (const bf16x8*)wp;
    const bf16x8 A1_0 = wf[0 * 64 + l], A1_1 = wf[1 * 64 + l];
    const bf16x8 A2_0 = wf[2 * 64 + l], A2_1 = wf[3 * 64 + l], A2_2 = wf[4 * 64 + l];
    const bf16x8 A3_00 = wf[5 * 64 + l], A3_01 = wf[6 * 64 + l];
    const bf16x8 A3_10 = wf[7 * 64 + l], A3_11 = wf[8 * 64 + l];
    const bf16x8 A3_20 = wf[9 * 64 + l], A3_21 = wf[10 * 64 + l];
    const bf16x8 A4_0 = wf[11 * 64 + l], A4_1 = wf[12 * 64 + l];

    const f32x4 zf = {0.0f, 0.0f, 0.0f, 0.0f};

    const float x0 = input[0 * N_PTS + i], x1 = input[1 * N_PTS + i];
    const float x2 = input[2 * N_PTS + i], x3 = input[3 * N_PTS + i];
    const unsigned xp01 = cvt_pk_bf16(x0, x1);
    const unsigned xp23 = cvt_pk_bf16(x2, x3);

    // ---- L1 ---- (R11 exact)
    unsigned P1[4][2][2];
#pragma unroll
    for (int t = 0; t < 4; ++t) {
        const unsigned srcl = (unsigned)(16 * t + c16);
        const unsigned bx0 = bperm_u(srcl, xp01);
        const unsigned bx1 = bperm_u(srcl, xp23);
        const bf16x8 B = mk_frag((g == 0) ? bx0 : 0u,
                                 (g == 0) ? bx1 : 0u,
                                 (g == 0) ? 0x3F80u : 0u, 0u);
        const f32x4 D0 = __builtin_amdgcn_mfma_f32_16x16x32_bf16(A1_0, B, zf, 0, 0, 0);
        const f32x4 D1 = __builtin_amdgcn_mfma_f32_16x16x32_bf16(A1_1, B, zf, 0, 0, 0);
        P1[t][0][0] = cvt_pk_bf16(fmaxf(D0.x, 0.f), fmaxf(D0.y, 0.f));
        P1[t][0][1] = cvt_pk_bf16(fmaxf(D0.z, 0.f), fmaxf(D0.w, 0.f));
        P1[t][1][0] = cvt_pk_bf16(fmaxf(D1.x, 0.f), fmaxf(D1.y, 0.f));
        P1[t][1][1] = cvt_pk_bf16(fmaxf(D1.z, 0.f), fmaxf(D1.w, 0.f));
    }

    // ---- L2: kappa self-pack ---- (R11 exact)
    unsigned P2[4][3][2];
#pragma unroll
    for (int t = 0; t < 4; ++t) {
        const bf16x8 B = mk_frag(P1[t][0][0], P1[t][0][1], P1[t][1][0],
                                 (g == 0) ? 0x3F80u : P1[t][1][1]);
        const f32x4 D0 = __builtin_amdgcn_mfma_f32_16x16x32_bf16(A2_0, B, zf, 0, 0, 0);
        const f32x4 D1 = __builtin_amdgcn_mfma_f32_16x16x32_bf16(A2_1, B, zf, 0, 0, 0);
        const f32x4 D2 = __builtin_amdgcn_mfma_f32_16x16x32_bf16(A2_2, B, zf, 0, 0, 0);
        P2[t][0][0] = cvt_pk_bf16(fmaxf(D0.x, 0.f), fmaxf(D0.y, 0.f));
        P2[t][0][1] = cvt_pk_bf16(fmaxf(D0.z, 0.f), fmaxf(D0.w, 0.f));
        P2[t][1][0] = cvt_pk_bf16(fmaxf(D1.x, 0.f), fmaxf(D1.y, 0.f));
        P2[t][1][1] = cvt_pk_bf16(fmaxf(D1.z, 0.f), fmaxf(D1.w, 0.f));
        P2[t][2][0] = cvt_pk_bf16(fmaxf(D2.x, 0.f), fmaxf(D2.y, 0.f));
        P2[t][2][1] = cvt_pk_bf16(fmaxf(D2.z, 0.f), fmaxf(D2.w, 0.f));
    }

    // ---- L3 ---- (R9-exact bperm gather)
    unsigned P3[4][3][2];
#pragma unroll
    for (int t = 0; t < 4; ++t) {
        unsigned dk0[4], dk1[4];
#pragma unroll
        for (int p = 0; p < 4; ++p) {
            const int Rl = (4 * g + p) & 7;
            const unsigned srcl = (unsigned)(c16 + 16 * (Rl >> 1));
            const unsigned lo = bperm_u(srcl, P2[t][0][p & 1]);
            const unsigned hi = bperm_u(srcl, P2[t][1][p & 1]);
            const unsigned m2 = bperm_u(srcl, P2[t][2][p & 1]);
            dk0[p] = (4 * g + p < 8) ? lo : hi;
            dk1[p] = (4 * g + p < 8) ? m2 : 0u;
        }
        if (g == 0) dk1[2] = (dk1[2] & 0xFFFF0000u) | 0x3F80u;
        const bf16x8 B0 = mk_frag(dk0[0], dk0[1], dk0[2], dk0[3]);
        const bf16x8 B1 = mk_frag(dk1[0], dk1[1], dk1[2], dk1[3]);
        f32x4 D0 = __builtin_amdgcn_mfma_f32_16x16x32_bf16(A3_00, B0, zf, 0, 0, 0);
        D0 = __builtin_amdgcn_mfma_f32_16x16x32_bf16(A3_01, B1, D0, 0, 0, 0);
        f32x4 D1 = __builtin_amdgcn_mfma_f32_16x16x32_bf16(A3_10, B0, zf, 0, 0, 0);
        D1 = __builtin_amdgcn_mfma_f32_16x16x32_bf16(A3_11, B1, D1, 0, 0, 0);
        f32x4 D2 = __builtin_amdgcn_mfma_f32_16x16x32_bf16(A3_20, B0, zf, 0, 0, 0);
        D2 = __builtin_amdgcn_mfma_f32_16x16x32_bf16(A3_21, B1, D2, 0, 0, 0);
        P3[t][0][0] = cvt_pk_bf16(fmaxf(D0.x, 0.f), fmaxf(D0.y, 0.f));
        P3[t][0][1] = cvt_pk_bf16(fmaxf(D0.z, 0.f), fmaxf(D0.w, 0.f));
        P3[t][1][0] = cvt_pk_bf16(fmaxf(D1.x, 0.f), fmaxf(D1.y, 0.f));
        P3[t][1][1] = cvt_pk_bf16(fmaxf(D1.z, 0.f), fmaxf(D1.w, 0.f));
        P3[t][2][0] = cvt_pk_bf16(fmaxf(D2.x, 0.f), fmaxf(D2.y, 0.f));
        P3[t][2][1] = cvt_pk_bf16(fmaxf(D2.z, 0.f), fmaxf(D2.w, 0.f));
    }

    // ---- L4 ---- (R9-exact)
    float vout[4];
#pragma unroll
    for (int t = 0; t < 4; ++t) {
        unsigned dk0[4], dk1[4];
#pragma unroll
        for (int p = 0; p < 4; ++p) {
            const int Rl = (4 * g + p) & 7;
            const unsigned srcl = (unsigned)(c16 + 16 * (Rl >> 1));
            const unsigned lo = bperm_u(srcl, P3[t][0][p & 1]);
            const unsigned hi = bperm_u(srcl, P3[t][1][p & 1]);
            const unsigned m2 = bperm_u(srcl, P3[t][2][p & 1]);
            dk0[p] = (4 * g + p < 8) ? lo : hi;
            dk1[p] = (4 * g + p < 8) ? m2 : 0u;
        }
        if (g == 0) dk1[2] = (dk1[2] & 0xFFFF0000u) | 0x3F80u;
        const bf16x8 B0 = mk_frag(dk0[0], dk0[1], dk0[2], dk0[3]);
        const bf16x8 B1 = mk_frag(dk1[0], dk1[1], dk1[2], dk1[3]);
        f32x4 D = __builtin_amdgcn_mfma_f32_16x16x32_bf16(A4_0, B0, zf, 0, 0, 0);
        D = __builtin_amdgcn_mfma_f32_16x16x32_bf16(A4_1, B1, D, 0, 0, 0);
        vout[t] = D.x;
    }

    // redistribute: point p's value sits in lane (p&15) of tile (p>>4)
    const unsigned r0 = bperm_u((unsigned)c16, __float_as_uint(vout[0]));
    const unsigned r1 = bperm_u((unsigned)c16, __float_as_uint(vout[1]));
    const unsigned r2 = bperm_u((unsigned)c16, __float_as_uint(vout[2]));
    const unsigned r3 = bperm_u((unsigned)c16, __float_as_uint(vout[3]));
    const unsigned vr = (g < 2) ? ((g == 0) ? r0 : r1) : ((g == 2) ? r2 : r3);

    feat[i] = vr;                           // coalesced value stream -- ONLY output
}

// Wave-local LDS ordering (colmax): drain this wave's DS ops.
__device__ __forceinline__ void lds_wave_fence() {
    asm volatile("s_waitcnt lgkmcnt(0)" ::: "memory");
}

// ---------------------------------------------------------------------------
// Kernel B (R13-verified, passed): 32-bit key dedup via ds_max_u32; winner
// value gathered from feat[key>>8] (L2); grid-stride 2200 x 4 waves.
// ---------------------------------------------------------------------------
__global__ void __launch_bounds__(256) colmax_kernel(
    const int* __restrict__ tindex,
    const int* __restrict__ counts,
    const unsigned* __restrict__ list4,
    const unsigned* __restrict__ feat,
    float* __restrict__ out,
    int maxk)
{
    __shared__ unsigned rowwin[4][200];
    const int lane = threadIdx.x;        // 0..63
    const int y    = threadIdx.y;        // 0..3
    unsigned* tbl = rowwin[y];

    const bool empty = (tindex[0] == -1);

    if (blockIdx.x == 0 && lane == 0 && y == 0)
        out[W_DIM] = empty ? 0.0f : 1.0f;    // flag output

    tbl[lane]       = 0u;
    tbl[lane + 64]  = 0u;
    tbl[lane + 128] = 0u;
    if (lane < 8) tbl[lane + 192] = 0u;
    lds_wave_fence();

    const int step = gridDim.x * 4;
    for (int w = blockIdx.x * 4 + y; w < W_DIM; w += step) {
        int c = 0;
        if (!empty) {
            c = counts[w];
            if (c > maxk) c = maxk;
        }

        unsigned e4 = 0u, fb = 0u;
        const bool have = (lane < c);
        float v = FILL_V;
        if (have) {
            e4 = list4[(size_t)w * maxk + lane];
            fb = feat[e4 >> 8];               // own point's value bits (L2)
            atomicMax(&tbl[e4 & 0xFFu], e4);  // native ds_max_u32
        }
        lds_wave_fence();
        if (have) {
            if (tbl[e4 & 0xFFu] == e4)        // unique keys -> one winner/row
                v = __uint_as_float(fb);
            tbl[e4 & 0xFFu] = 0u;
        }
        lds_wave_fence();

#pragma unroll
        for (int off = 32; off > 0; off >>= 1)
            v = fmaxf(v, __shfl_down(v, off, 64));

        if (lane == 0) out[w] = v;
    }
}

extern "C" void kernel_launch(void* const* d_in, const int* in_sizes, int n_in,
                              void* d_out, int out_size, void* d_ws, size_t ws_size,
                              hipStream_t stream) {
    const float* input  = (const float*)d_in[0];
    const int*   tindex = (const int*)d_in[1];   // int32 on device
    const float* w1 = (const float*)d_in[2];
    const float* b1 = (const float*)d_in[3];
    const float* w2 = (const float*)d_in[4];
    const float* b2 = (const float*)d_in[5];
    const float* w3 = (const float*)d_in[6];
    const float* b3 = (const float*)d_in[7];
    const float* w4 = (const float*)d_in[8];
    const float* b4 = (const float*)d_in[9];
    float* out = (float*)d_out;

    int*            counts = (int*)d_ws;
    unsigned short* wpack  = (unsigned short*)((char*)d_ws + COUNTS_BYTES);
    unsigned*       feat   = (unsigned*)((char*)d_ws + COUNTS_BYTES + WPACK_BYTES);
    unsigned*       list4  = (unsigned*)((char*)d_ws + COUNTS_BYTES + WPACK_BYTES + FEAT_BYTES);

    size_t head = COUNTS_BYTES + WPACK_BYTES + FEAT_BYTES;
    size_t avail = (ws_size > head) ? ws_size - head : 0;
    int maxk = (int)(avail / ((size_t)W_DIM * sizeof(unsigned)));
    if (maxk > 64) maxk = 64;
    if (maxk < 1)  maxk = 1;

    (void)hipMemsetAsync(counts, 0, COUNTS_BYTES, stream);

    pack_weights_kernel<<<1, 256, 0, stream>>>(w1, b1, w2, b2, w3, b3, w4, b4, wpack);

    // Kernel S: scatter bookkeeping in a pure-memory regime (1M atomics,
    // 524K threads, ~2 pts each). Separately measurable in the counters.
    slot_kernel<<<2048, 256, 0, stream>>>(tindex, counts, list4, maxk);

    // Kernel A: pure compute + coalesced feat write (no atomics, no scatter).
    mlp_feat_kernel<<<(N_PTS / 64 + 3) / 4, 256, 0, stream>>>(
        input, tindex, wpack, feat);

    colmax_kernel<<<2200, dim3(64, 4), 0, stream>>>(
        tindex, counts, list4, feat, out, maxk);
}

// Round 16
// 178.710 us; speedup vs baseline: 1.1806x; 1.1806x over previous
//
#include <hip/hip_runtime.h>

#define N_PTS 1000000
#define H_DIM 200
#define W_DIM 70400
#define FILL_V -9999999.0f
#define OCT_W 8800              // columns per octant = W_DIM/8

// ws layout: counts[W int] | wpack[6656 bf16] | feat[1M u32] | list4[W][maxk] u32
#define COUNTS_BYTES ((size_t)W_DIM * sizeof(int))
#define WPACK_ELEMS  6656
#define WPACK_BYTES  ((size_t)WPACK_ELEMS * 2)
#define FEAT_BYTES   ((size_t)N_PTS * 4)

typedef __attribute__((ext_vector_type(4))) float f32x4;
typedef __attribute__((ext_vector_type(8))) short bf16x8;

__device__ __forceinline__ unsigned bperm_u(unsigned src_lane, unsigned v) {
    return (unsigned)__builtin_amdgcn_ds_bpermute((int)(src_lane << 2), (int)v);
}
__device__ __forceinline__ unsigned cvt_pk_bf16(float lo, float hi) {
    unsigned d;
    asm("v_cvt_pk_bf16_f32 %0, %1, %2" : "=v"(d) : "v"(lo), "v"(hi));
    return d;
}
__device__ __forceinline__ bf16x8 mk_frag(unsigned d0, unsigned d1,
                                          unsigned d2, unsigned d3) {
    union { unsigned u[4]; bf16x8 s; } u;
    u.u[0] = d0; u.u[1] = d1; u.u[2] = d2; u.u[3] = d3;
    return u.s;
}

// ---------------------------------------------------------------------------
// Prep (unchanged from R11, verified): A2 kappa'd, A1/A3/A4 linear.
// ---------------------------------------------------------------------------
__global__ void __launch_bounds__(256) pack_weights_kernel(
    const float* __restrict__ w1, const float* __restrict__ b1,
    const float* __restrict__ w2, const float* __restrict__ b2,
    const float* __restrict__ w3, const float* __restrict__ b3,
    const float* __restrict__ w4, const float* __restrict__ b4,
    unsigned short* __restrict__ wp)
{
    for (int idx = threadIdx.x; idx < WPACK_ELEMS; idx += 256) {
        const int rem  = idx & 511;
        const int lane = rem >> 3, j = rem & 7;
        const int c16 = lane & 15, gk = lane >> 4;
        const int kloc = gk * 8 + j;
        float v = 0.0f;
        if (idx < 1024) {                       // A1: linear
            const int row = (idx >> 9) * 16 + c16, k = kloc;
            if (row < 18) v = (k < 4) ? w1[row * 4 + k] : (k == 4 ? b1[row] : 0.0f);
        } else if (idx < 2560) {                // A2: KAPPA (R11-verified)
            const int row = ((idx - 1024) >> 9) * 16 + c16;
            const int f = (j < 4) ? (4 * gk + j) : (16 + 4 * gk + (j - 4));
            if (row < 36) v = (f < 18) ? w2[row * 18 + f] : (f == 18 ? b2[row] : 0.0f);
        } else if (idx < 5632) {                // A3: linear
            const int f = (idx - 2560) >> 9;
            const int row = (f >> 1) * 16 + c16, k = (f & 1) * 32 + kloc;
            if (row < 36) v = (k < 36) ? w3[row * 36 + k] : (k == 36 ? b3[row] : 0.0f);
        } else {                                // A4: linear
            const int row = c16, k = ((idx - 5632) >> 9) * 32 + kloc;
            if (row == 0) v = (k < 36) ? w4[k] : (k == 36 ? b4[0] : 0.0f);
        }
        const unsigned b = __float_as_uint(v);  // f32 -> bf16 RNE
        wp[idx] = (unsigned short)((b + 0x7FFFu + ((b >> 16) & 1u)) >> 16);
    }
}

// ---------------------------------------------------------------------------
// Kernel S v2 (R16): COLUMN-OCTANT-PARTITIONED scatter bookkeeping.
// R15 isolated the wall: scatter alone = 81us / 60MB WRITE at 0.5% VALU.
// Footprint (18MB) fits aggregate L2, so the traffic is cross-XCD line
// BOUNCING: each column's slot/counter lines get ~14 appends from ~7
// different non-coherent L2s -> writeback+refetch per ownership change
// (~70400 lines x ~12 x 64B ~= 54MB = the invariant WRITE_SIZE).
// Fix: blocks with blockIdx&7==o process ONLY columns in octant o
// (col/8800). With round-robin block->XCD placement, octant o's 2.3MB
// slice lives in ONE L2: atomics+appends L2-local, writeback = footprint.
// Correctness is mapping-independent: blocks 8k..8k+7 share scan range
// [tid, N) stride 65536, one block per octant -> each point processed
// exactly once. Cost: tindex read x8 = 64MB (~10us streaming).
// ---------------------------------------------------------------------------
__global__ void __launch_bounds__(256) slot_kernel(
    const int* __restrict__ tindex,
    int* __restrict__ counts,
    unsigned* __restrict__ list4,
    int maxk)
{
    if (tindex[0] == -1) return;            // empty-branch: no scatter at all
    const unsigned oct = (unsigned)(blockIdx.x & 7);
    const int tid = (int)((blockIdx.x >> 3) * 256 + threadIdx.x);   // 0..65535
    for (int i = tid; i < N_PTS; i += 65536) {
        const int2 hw = ((const int2*)tindex)[i];   // (row, col)
        if ((unsigned)hw.y / OCT_W == oct) {        // magic-mul divide
            const int pos = atomicAdd(&counts[hw.y], 1);
            if (pos < maxk)
                list4[(size_t)hw.y * maxk + pos] = ((unsigned)i << 8) | (unsigned)hw.x;
        }
    }
}

// ---------------------------------------------------------------------------
// Kernel A v12 (R15-verbatim, passed): R11-verified MFMA body, no scatter.
// Only output: coalesced feat[i] stream (4MB).
// ---------------------------------------------------------------------------
__global__ void __launch_bounds__(256) mlp_feat_kernel(
    const float* __restrict__ input,        // [4][N]
    const int* __restrict__ tindex,         // empty-branch check only
    const unsigned short* __restrict__ wp,  // packed bf16 fragments
    unsigned* __restrict__ feat)            // [N] value bits, linear
{
    if (tindex[0] == -1) return;            // empty-branch

    const int l   = threadIdx.x & 63;
    const int wav = (blockIdx.x * 256 + threadIdx.x) >> 6;
    const int base = wav << 6;
    if (base >= N_PTS) return;              // whole-wave early out (N%64==0)
    const int i = base + l;
    const int c16 = l & 15, g = l >> 4;

    const bf16x8* __restrict__ wf = (const bf16x8*)wp;
    const bf16x8 A1_0 = wf[0 * 64 + l], A1_1 = wf[1 * 64 + l];
    const bf16x8 A2_0 = wf[2 * 64 + l], A2_1 = wf[3 * 64 + l], A2_2 = wf[4 * 64 + l];
    const bf16x8 A3_00 = wf[5 * 64 + l], A3_01 = wf[6 * 64 + l];
    const bf16x8 A3_10 = wf[7 * 64 + l], A3_11 = wf[8 * 64 + l];
    const bf16x8 A3_20 = wf[9 * 64 + l], A3_21 = wf[10 * 64 + l];
    const bf16x8 A4_0 = wf[11 * 64 + l], A4_1 = wf[12 * 64 + l];

    const f32x4 zf = {0.0f, 0.0f, 0.0f, 0.0f};

    const float x0 = input[0 * N_PTS + i], x1 = input[1 * N_PTS + i];
    const float x2 = input[2 * N_PTS + i], x3 = input[3 * N_PTS + i];
    const unsigned xp01 = cvt_pk_bf16(x0, x1);
    const unsigned xp23 = cvt_pk_bf16(x2, x3);

    // ---- L1 ---- (R11 exact)
    unsigned P1[4][2][2];
#pragma unroll
    for (int t = 0; t < 4; ++t) {
        const unsigned srcl = (unsigned)(16 * t + c16);
        const unsigned bx0 = bperm_u(srcl, xp01);
        const unsigned bx1 = bperm_u(srcl, xp23);
        const bf16x8 B = mk_frag((g == 0) ? bx0 : 0u,
                                 (g == 0) ? bx1 : 0u,
                                 (g == 0) ? 0x3F80u : 0u, 0u);
        const f32x4 D0 = __builtin_amdgcn_mfma_f32_16x16x32_bf16(A1_0, B, zf, 0, 0, 0);
        const f32x4 D1 = __builtin_amdgcn_mfma_f32_16x16x32_bf16(A1_1, B, zf, 0, 0, 0);
        P1[t][0][0] = cvt_pk_bf16(fmaxf(D0.x, 0.f), fmaxf(D0.y, 0.f));
        P1[t][0][1] = cvt_pk_bf16(fmaxf(D0.z, 0.f), fmaxf(D0.w, 0.f));
        P1[t][1][0] = cvt_pk_bf16(fmaxf(D1.x, 0.f), fmaxf(D1.y, 0.f));
        P1[t][1][1] = cvt_pk_bf16(fmaxf(D1.z, 0.f), fmaxf(D1.w, 0.f));
    }

    // ---- L2: kappa self-pack ---- (R11 exact)
    unsigned P2[4][3][2];
#pragma unroll
    for (int t = 0; t < 4; ++t) {
        const bf16x8 B = mk_frag(P1[t][0][0], P1[t][0][1], P1[t][1][0],
                                 (g == 0) ? 0x3F80u : P1[t][1][1]);
        const f32x4 D0 = __builtin_amdgcn_mfma_f32_16x16x32_bf16(A2_0, B, zf, 0, 0, 0);
        const f32x4 D1 = __builtin_amdgcn_mfma_f32_16x16x32_bf16(A2_1, B, zf, 0, 0, 0);
        const f32x4 D2 = __builtin_amdgcn_mfma_f32_16x16x32_bf16(A2_2, B, zf, 0, 0, 0);
        P2[t][0][0] = cvt_pk_bf16(fmaxf(D0.x, 0.f), fmaxf(D0.y, 0.f));
        P2[t][0][1] = cvt_pk_bf16(fmaxf(D0.z, 0.f), fmaxf(D0.w, 0.f));
        P2[t][1][0] = cvt_pk_bf16(fmaxf(D1.x, 0.f), fmaxf(D1.y, 0.f));
        P2[t][1][1] = cvt_pk_bf16(fmaxf(D1.z, 0.f), fmaxf(D1.w, 0.f));
        P2[t][2][0] = cvt_pk_bf16(fmaxf(D2.x, 0.f), fmaxf(D2.y, 0.f));
        P2[t][2][1] = cvt_pk_bf16(fmaxf(D2.z, 0.f), fmaxf(D2.w, 0.f));
    }

    // ---- L3 ---- (R9-exact bperm gather)
    unsigned P3[4][3][2];
#pragma unroll
    for (int t = 0; t < 4; ++t) {
        unsigned dk0[4], dk1[4];
#pragma unroll
        for (int p = 0; p < 4; ++p) {
            const int Rl = (4 * g + p) & 7;
            const unsigned srcl = (unsigned)(c16 + 16 * (Rl >> 1));
            const unsigned lo = bperm_u(srcl, P2[t][0][p & 1]);
            const unsigned hi = bperm_u(srcl, P2[t][1][p & 1]);
            const unsigned m2 = bperm_u(srcl, P2[t][2][p & 1]);
            dk0[p] = (4 * g + p < 8) ? lo : hi;
            dk1[p] = (4 * g + p < 8) ? m2 : 0u;
        }
        if (g == 0) dk1[2] = (dk1[2] & 0xFFFF0000u) | 0x3F80u;
        const bf16x8 B0 = mk_frag(dk0[0], dk0[1], dk0[2], dk0[3]);
        const bf16x8 B1 = mk_frag(dk1[0], dk1[1], dk1[2], dk1[3]);
        f32x4 D0 = __builtin_amdgcn_mfma_f32_16x16x32_bf16(A3_00, B0, zf, 0, 0, 0);
        D0 = __builtin_amdgcn_mfma_f32_16x16x32_bf16(A3_01, B1, D0, 0, 0, 0);
        f32x4 D1 = __builtin_amdgcn_mfma_f32_16x16x32_bf16(A3_10, B0, zf, 0, 0, 0);
        D1 = __builtin_amdgcn_mfma_f32_16x16x32_bf16(A3_11, B1, D1, 0, 0, 0);
        f32x4 D2 = __builtin_amdgcn_mfma_f32_16x16x32_bf16(A3_20, B0, zf, 0, 0, 0);
        D2 = __builtin_amdgcn_mfma_f32_16x16x32_bf16(A3_21, B1, D2, 0, 0, 0);
        P3[t][0][0] = cvt_pk_bf16(fmaxf(D0.x, 0.f), fmaxf(D0.y, 0.f));
        P3[t][0][1] = cvt_pk_bf16(fmaxf(D0.z, 0.f), fmaxf(D0.w, 0.f));
        P3[t][1][0] = cvt_pk_bf16(fmaxf(D1.x, 0.f), fmaxf(D1.y, 0.f));
        P3[t][1][1] = cvt_pk_bf16(fmaxf(D1.z, 0.f), fmaxf(D1.w, 0.f));
        P3[t][2][0] = cvt_pk_bf16(fmaxf(D2.x, 0.f), fmaxf(D2.y, 0.f));
        P3[t][2][1] = cvt_pk_bf16(fmaxf(D2.z, 0.f), fmaxf(D2.w, 0.f));
    }

    // ---- L4 ---- (R9-exact)
    float vout[4];
#pragma unroll
    for (int t = 0; t < 4; ++t) {
        unsigned dk0[4], dk1[4];
#pragma unroll
        for (int p = 0; p < 4; ++p) {
            const int Rl = (4 * g + p) & 7;
            const unsigned srcl = (unsigned)(c16 + 16 * (Rl >> 1));
            const unsigned lo = bperm_u(srcl, P3[t][0][p & 1]);
            const unsigned hi = bperm_u(srcl, P3[t][1][p & 1]);
            const unsigned m2 = bperm_u(srcl, P3[t][2][p & 1]);
            dk0[p] = (4 * g + p < 8) ? lo : hi;
            dk1[p] = (4 * g + p < 8) ? m2 : 0u;
        }
        if (g == 0) dk1[2] = (dk1[2] & 0xFFFF0000u) | 0x3F80u;
        const bf16x8 B0 = mk_frag(dk0[0], dk0[1], dk0[2], dk0[3]);
        const bf16x8 B1 = mk_frag(dk1[0], dk1[1], dk1[2], dk1[3]);
        f32x4 D = __builtin_amdgcn_mfma_f32_16x16x32_bf16(A4_0, B0, zf, 0, 0, 0);
        D = __builtin_amdgcn_mfma_f32_16x16x32_bf16(A4_1, B1, D, 0, 0, 0);
        vout[t] = D.x;
    }

    // redistribute: point p's value sits in lane (p&15) of tile (p>>4)
    const unsigned r0 = bperm_u((unsigned)c16, __float_as_uint(vout[0]));
    const unsigned r1 = bperm_u((unsigned)c16, __float_as_uint(vout[1]));
    const unsigned r2 = bperm_u((unsigned)c16, __float_as_uint(vout[2]));
    const unsigned r3 = bperm_u((unsigned)c16, __float_as_uint(vout[3]));
    const unsigned vr = (g < 2) ? ((g == 0) ? r0 : r1) : ((g == 2) ? r2 : r3);

    feat[i] = vr;                           // coalesced value stream -- ONLY output
}

// Wave-local LDS ordering (colmax): drain this wave's DS ops.
__device__ __forceinline__ void lds_wave_fence() {
    asm volatile("s_waitcnt lgkmcnt(0)" ::: "memory");
}

// ---------------------------------------------------------------------------
// Kernel B v6 (R16): R13-verified dedup body, columns remapped to OCTANTS so
// each block reads the list slice its (likely) own XCD just wrote.
// 2200 blocks = 8 octants x 275 groups; wave y of group grp covers
// w = oct*8800 + (grp*4+y) + k*1100, k=0..7  -> exactly 8800 cols/octant.
// ---------------------------------------------------------------------------
__global__ void __launch_bounds__(256) colmax_kernel(
    const int* __restrict__ tindex,
    const int* __restrict__ counts,
    const unsigned* __restrict__ list4,
    const unsigned* __restrict__ feat,
    float* __restrict__ out,
    int maxk)
{
    __shared__ unsigned rowwin[4][200];
    const int lane = threadIdx.x;        // 0..63
    const int y    = threadIdx.y;        // 0..3
    unsigned* tbl = rowwin[y];

    const bool empty = (tindex[0] == -1);

    if (blockIdx.x == 0 && lane == 0 && y == 0)
        out[W_DIM] = empty ? 0.0f : 1.0f;    // flag output

    tbl[lane]       = 0u;
    tbl[lane + 64]  = 0u;
    tbl[lane + 128] = 0u;
    if (lane < 8) tbl[lane + 192] = 0u;
    lds_wave_fence();

    const int oct = blockIdx.x & 7;
    const int grp = blockIdx.x >> 3;     // 0..274
    const int wbase = oct * OCT_W + grp * 4 + y;

#pragma unroll
    for (int k = 0; k < 8; ++k) {
        const int w = wbase + k * 1100;  // covers [oct*8800, oct*8800+8800)

        int c = 0;
        if (!empty) {
            c = counts[w];
            if (c > maxk) c = maxk;
        }

        unsigned e4 = 0u, fb = 0u;
        const bool have = (lane < c);
        float v = FILL_V;
        if (have) {
            e4 = list4[(size_t)w * maxk + lane];
            fb = feat[e4 >> 8];               // own point's value bits (L2)
            atomicMax(&tbl[e4 & 0xFFu], e4);  // native ds_max_u32
        }
        lds_wave_fence();
        if (have) {
            if (tbl[e4 & 0xFFu] == e4)        // unique keys -> one winner/row
                v = __uint_as_float(fb);
            tbl[e4 & 0xFFu] = 0u;
        }
        lds_wave_fence();

#pragma unroll
        for (int off = 32; off > 0; off >>= 1)
            v = fmaxf(v, __shfl_down(v, off, 64));

        if (lane == 0) out[w] = v;
    }
}

extern "C" void kernel_launch(void* const* d_in, const int* in_sizes, int n_in,
                              void* d_out, int out_size, void* d_ws, size_t ws_size,
                              hipStream_t stream) {
    const float* input  = (const float*)d_in[0];
    const int*   tindex = (const int*)d_in[1];   // int32 on device
    const float* w1 = (const float*)d_in[2];
    const float* b1 = (const float*)d_in[3];
    const float* w2 = (const float*)d_in[4];
    const float* b2 = (const float*)d_in[5];
    const float* w3 = (const float*)d_in[6];
    const float* b3 = (const float*)d_in[7];
    const float* w4 = (const float*)d_in[8];
    const float* b4 = (const float*)d_in[9];
    float* out = (float*)d_out;

    int*            counts = (int*)d_ws;
    unsigned short* wpack  = (unsigned short*)((char*)d_ws + COUNTS_BYTES);
    unsigned*       feat   = (unsigned*)((char*)d_ws + COUNTS_BYTES + WPACK_BYTES);
    unsigned*       list4  = (unsigned*)((char*)d_ws + COUNTS_BYTES + WPACK_BYTES + FEAT_BYTES);

    size_t head = COUNTS_BYTES + WPACK_BYTES + FEAT_BYTES;
    size_t avail = (ws_size > head) ? ws_size - head : 0;
    int maxk = (int)(avail / ((size_t)W_DIM * sizeof(unsigned)));
    if (maxk > 64) maxk = 64;
    if (maxk < 1)  maxk = 1;

    (void)hipMemsetAsync(counts, 0, COUNTS_BYTES, stream);

    pack_weights_kernel<<<1, 256, 0, stream>>>(w1, b1, w2, b2, w3, b3, w4, b4, wpack);

    // Octant-partitioned scatter: 2048 blocks, blockIdx&7 = column octant.
    slot_kernel<<<2048, 256, 0, stream>>>(tindex, counts, list4, maxk);

    // Pure compute + coalesced feat write.
    mlp_feat_kernel<<<(N_PTS / 64 + 3) / 4, 256, 0, stream>>>(
        input, tindex, wpack, feat);

    // Octant-partitioned colmax: 2200 = 8 octants x 275 groups.
    colmax_kernel<<<2200, dim3(64, 4), 0, stream>>>(
        tindex, counts, list4, feat, out, maxk);
}

// Round 17
// 168.452 us; speedup vs baseline: 1.2525x; 1.0609x over previous
//
#include <hip/hip_runtime.h>

#define N_PTS 1000000
#define H_DIM 200
#define W_DIM 70400
#define FILL_V -9999999.0f
#define OCT_W 8800              // columns per octant = W_DIM/8
#define SLOT_BLKS 2048          // blocks [0,2048): octant scatter
#define MLP_BLKS  3907          // blocks [2048, 2048+3907): MFMA mlp

// ws layout: counts[W int] | wpack[6656 bf16] | feat[1M u32] | list4[W][maxk] u32
#define COUNTS_BYTES ((size_t)W_DIM * sizeof(int))
#define WPACK_ELEMS  6656
#define WPACK_BYTES  ((size_t)WPACK_ELEMS * 2)
#define FEAT_BYTES   ((size_t)N_PTS * 4)

typedef __attribute__((ext_vector_type(4))) float f32x4;
typedef __attribute__((ext_vector_type(8))) short bf16x8;

__device__ __forceinline__ unsigned bperm_u(unsigned src_lane, unsigned v) {
    return (unsigned)__builtin_amdgcn_ds_bpermute((int)(src_lane << 2), (int)v);
}
__device__ __forceinline__ unsigned cvt_pk_bf16(float lo, float hi) {
    unsigned d;
    asm("v_cvt_pk_bf16_f32 %0, %1, %2" : "=v"(d) : "v"(lo), "v"(hi));
    return d;
}
__device__ __forceinline__ bf16x8 mk_frag(unsigned d0, unsigned d1,
                                          unsigned d2, unsigned d3) {
    union { unsigned u[4]; bf16x8 s; } u;
    u.u[0] = d0; u.u[1] = d1; u.u[2] = d2; u.u[3] = d3;
    return u.s;
}

// ---------------------------------------------------------------------------
// Prep (unchanged from R11, verified): A2 kappa'd, A1/A3/A4 linear.
// ---------------------------------------------------------------------------
__global__ void __launch_bounds__(256) pack_weights_kernel(
    const float* __restrict__ w1, const float* __restrict__ b1,
    const float* __restrict__ w2, const float* __restrict__ b2,
    const float* __restrict__ w3, const float* __restrict__ b3,
    const float* __restrict__ w4, const float* __restrict__ b4,
    unsigned short* __restrict__ wp)
{
    for (int idx = threadIdx.x; idx < WPACK_ELEMS; idx += 256) {
        const int rem  = idx & 511;
        const int lane = rem >> 3, j = rem & 7;
        const int c16 = lane & 15, gk = lane >> 4;
        const int kloc = gk * 8 + j;
        float v = 0.0f;
        if (idx < 1024) {                       // A1: linear
            const int row = (idx >> 9) * 16 + c16, k = kloc;
            if (row < 18) v = (k < 4) ? w1[row * 4 + k] : (k == 4 ? b1[row] : 0.0f);
        } else if (idx < 2560) {                // A2: KAPPA (R11-verified)
            const int row = ((idx - 1024) >> 9) * 16 + c16;
            const int f = (j < 4) ? (4 * gk + j) : (16 + 4 * gk + (j - 4));
            if (row < 36) v = (f < 18) ? w2[row * 18 + f] : (f == 18 ? b2[row] : 0.0f);
        } else if (idx < 5632) {                // A3: linear
            const int f = (idx - 2560) >> 9;
            const int row = (f >> 1) * 16 + c16, k = (f & 1) * 32 + kloc;
            if (row < 36) v = (k < 36) ? w3[row * 36 + k] : (k == 36 ? b3[row] : 0.0f);
        } else {                                // A4: linear
            const int row = c16, k = ((idx - 5632) >> 9) * 32 + kloc;
            if (row == 0) v = (k < 36) ? w4[k] : (k == 36 ? b4[0] : 0.0f);
        }
        const unsigned b = __float_as_uint(v);  // f32 -> bf16 RNE
        wp[idx] = (unsigned short)((b + 0x7FFFu + ((b >> 16) & 1u)) >> 16);
    }
}

// ---------------------------------------------------------------------------
// R17 WORK KERNEL: block-specialized fusion of two INDEPENDENT phases.
// R16 post-mortem: octant scatter works (81->45us, WRITE 60->43MB) but the
// 3-kernel split SERIALIZED slot(45)+mlp(28); harness floor measured at
// ~85-90us (2x 256MB fillBuffer@45us + ~13 restores) -> our budget is the
// kernel sum. Fix: one dispatch, disjoint block ranges. Blocks [0,2048):
// R16-verified octant scatter (launched first -- longer leg, 8-VGPR
// memory-latency path). Blocks [2048,5955): R15-verified MFMA body (issue
// bound, 12MB fetch). Independent outputs (counts/list4 vs feat) -> no
// sync needed; colmax consumes both in the next dispatch. SLOT_BLKS%8==0
// keeps blockIdx&7 == octant for the scatter range (round-robin XCD map).
// Predicted: ~50-58us vs 73 serialized. If ~73 -> CP serializes ranges;
// revert to R13 fused-per-wave as terminal.
// ---------------------------------------------------------------------------
__global__ void __launch_bounds__(256) work_kernel(
    const float* __restrict__ input,        // [4][N]
    const int* __restrict__ tindex,         // [N][2] int32 (row, col)
    const unsigned short* __restrict__ wp,  // packed bf16 fragments
    int* __restrict__ counts,               // [W]
    unsigned* __restrict__ feat,            // [N] value bits, linear
    unsigned* __restrict__ list4,           // [W][maxk] keys
    int maxk)
{
    if (tindex[0] == -1) return;            // empty-branch (both phases)

    if (blockIdx.x < SLOT_BLKS) {
        // ---------------- octant scatter (R16-verbatim) ----------------
        const unsigned oct = (unsigned)(blockIdx.x & 7);
        const int tid = (int)((blockIdx.x >> 3) * 256 + threadIdx.x);   // 0..65535
        for (int i = tid; i < N_PTS; i += 65536) {
            const int2 hw = ((const int2*)tindex)[i];   // (row, col)
            if ((unsigned)hw.y / OCT_W == oct) {
                const int pos = atomicAdd(&counts[hw.y], 1);
                if (pos < maxk)
                    list4[(size_t)hw.y * maxk + pos] =
                        ((unsigned)i << 8) | (unsigned)hw.x;
            }
        }
        return;
    }

    // ---------------- MFMA mlp -> feat (R15-verbatim) ----------------
    const int l   = threadIdx.x & 63;
    const int wav = (int)(((blockIdx.x - SLOT_BLKS) * 256 + threadIdx.x) >> 6);
    const int base = wav << 6;
    if (base >= N_PTS) return;              // whole-wave early out (N%64==0)
    const int i = base + l;
    const int c16 = l & 15, g = l >> 4;

    const bf16x8* __restrict__ wf = (const bf16x8*)wp;
    const bf16x8 A1_0 = wf[0 * 64 + l], A1_1 = wf[1 * 64 + l];
    const bf16x8 A2_0 = wf[2 * 64 + l], A2_1 = wf[3 * 64 + l], A2_2 = wf[4 * 64 + l];
    const bf16x8 A3_00 = wf[5 * 64 + l], A3_01 = wf[6 * 64 + l];
    const bf16x8 A3_10 = wf[7 * 64 + l], A3_11 = wf[8 * 64 + l];
    const bf16x8 A3_20 = wf[9 * 64 + l], A3_21 = wf[10 * 64 + l];
    const bf16x8 A4_0 = wf[11 * 64 + l], A4_1 = wf[12 * 64 + l];

    const f32x4 zf = {0.0f, 0.0f, 0.0f, 0.0f};

    const float x0 = input[0 * N_PTS + i], x1 = input[1 * N_PTS + i];
    const float x2 = input[2 * N_PTS + i], x3 = input[3 * N_PTS + i];
    const unsigned xp01 = cvt_pk_bf16(x0, x1);
    const unsigned xp23 = cvt_pk_bf16(x2, x3);

    // ---- L1 ---- (R11 exact)
    unsigned P1[4][2][2];
#pragma unroll
    for (int t = 0; t < 4; ++t) {
        const unsigned srcl = (unsigned)(16 * t + c16);
        const unsigned bx0 = bperm_u(srcl, xp01);
        const unsigned bx1 = bperm_u(srcl, xp23);
        const bf16x8 B = mk_frag((g == 0) ? bx0 : 0u,
                                 (g == 0) ? bx1 : 0u,
                                 (g == 0) ? 0x3F80u : 0u, 0u);
        const f32x4 D0 = __builtin_amdgcn_mfma_f32_16x16x32_bf16(A1_0, B, zf, 0, 0, 0);
        const f32x4 D1 = __builtin_amdgcn_mfma_f32_16x16x32_bf16(A1_1, B, zf, 0, 0, 0);
        P1[t][0][0] = cvt_pk_bf16(fmaxf(D0.x, 0.f), fmaxf(D0.y, 0.f));
        P1[t][0][1] = cvt_pk_bf16(fmaxf(D0.z, 0.f), fmaxf(D0.w, 0.f));
        P1[t][1][0] = cvt_pk_bf16(fmaxf(D1.x, 0.f), fmaxf(D1.y, 0.f));
        P1[t][1][1] = cvt_pk_bf16(fmaxf(D1.z, 0.f), fmaxf(D1.w, 0.f));
    }

    // ---- L2: kappa self-pack ---- (R11 exact)
    unsigned P2[4][3][2];
#pragma unroll
    for (int t = 0; t < 4; ++t) {
        const bf16x8 B = mk_frag(P1[t][0][0], P1[t][0][1], P1[t][1][0],
                                 (g == 0) ? 0x3F80u : P1[t][1][1]);
        const f32x4 D0 = __builtin_amdgcn_mfma_f32_16x16x32_bf16(A2_0, B, zf, 0, 0, 0);
        const f32x4 D1 = __builtin_amdgcn_mfma_f32_16x16x32_bf16(A2_1, B, zf, 0, 0, 0);
        const f32x4 D2 = __builtin_amdgcn_mfma_f32_16x16x32_bf16(A2_2, B, zf, 0, 0, 0);
        P2[t][0][0] = cvt_pk_bf16(fmaxf(D0.x, 0.f), fmaxf(D0.y, 0.f));
        P2[t][0][1] = cvt_pk_bf16(fmaxf(D0.z, 0.f), fmaxf(D0.w, 0.f));
        P2[t][1][0] = cvt_pk_bf16(fmaxf(D1.x, 0.f), fmaxf(D1.y, 0.f));
        P2[t][1][1] = cvt_pk_bf16(fmaxf(D1.z, 0.f), fmaxf(D1.w, 0.f));
        P2[t][2][0] = cvt_pk_bf16(fmaxf(D2.x, 0.f), fmaxf(D2.y, 0.f));
        P2[t][2][1] = cvt_pk_bf16(fmaxf(D2.z, 0.f), fmaxf(D2.w, 0.f));
    }

    // ---- L3 ---- (R9-exact bperm gather)
    unsigned P3[4][3][2];
#pragma unroll
    for (int t = 0; t < 4; ++t) {
        unsigned dk0[4], dk1[4];
#pragma unroll
        for (int p = 0; p < 4; ++p) {
            const int Rl = (4 * g + p) & 7;
            const unsigned srcl = (unsigned)(c16 + 16 * (Rl >> 1));
            const unsigned lo = bperm_u(srcl, P2[t][0][p & 1]);
            const unsigned hi = bperm_u(srcl, P2[t][1][p & 1]);
            const unsigned m2 = bperm_u(srcl, P2[t][2][p & 1]);
            dk0[p] = (4 * g + p < 8) ? lo : hi;
            dk1[p] = (4 * g + p < 8) ? m2 : 0u;
        }
        if (g == 0) dk1[2] = (dk1[2] & 0xFFFF0000u) | 0x3F80u;
        const bf16x8 B0 = mk_frag(dk0[0], dk0[1], dk0[2], dk0[3]);
        const bf16x8 B1 = mk_frag(dk1[0], dk1[1], dk1[2], dk1[3]);
        f32x4 D0 = __builtin_amdgcn_mfma_f32_16x16x32_bf16(A3_00, B0, zf, 0, 0, 0);
        D0 = __builtin_amdgcn_mfma_f32_16x16x32_bf16(A3_01, B1, D0, 0, 0, 0);
        f32x4 D1 = __builtin_amdgcn_mfma_f32_16x16x32_bf16(A3_10, B0, zf, 0, 0, 0);
        D1 = __builtin_amdgcn_mfma_f32_16x16x32_bf16(A3_11, B1, D1, 0, 0, 0);
        f32x4 D2 = __builtin_amdgcn_mfma_f32_16x16x32_bf16(A3_20, B0, zf, 0, 0, 0);
        D2 = __builtin_amdgcn_mfma_f32_16x16x32_bf16(A3_21, B1, D2, 0, 0, 0);
        P3[t][0][0] = cvt_pk_bf16(fmaxf(D0.x, 0.f), fmaxf(D0.y, 0.f));
        P3[t][0][1] = cvt_pk_bf16(fmaxf(D0.z, 0.f), fmaxf(D0.w, 0.f));
        P3[t][1][0] = cvt_pk_bf16(fmaxf(D1.x, 0.f), fmaxf(D1.y, 0.f));
        P3[t][1][1] = cvt_pk_bf16(fmaxf(D1.z, 0.f), fmaxf(D1.w, 0.f));
        P3[t][2][0] = cvt_pk_bf16(fmaxf(D2.x, 0.f), fmaxf(D2.y, 0.f));
        P3[t][2][1] = cvt_pk_bf16(fmaxf(D2.z, 0.f), fmaxf(D2.w, 0.f));
    }

    // ---- L4 ---- (R9-exact)
    float vout[4];
#pragma unroll
    for (int t = 0; t < 4; ++t) {
        unsigned dk0[4], dk1[4];
#pragma unroll
        for (int p = 0; p < 4; ++p) {
            const int Rl = (4 * g + p) & 7;
            const unsigned srcl = (unsigned)(c16 + 16 * (Rl >> 1));
            const unsigned lo = bperm_u(srcl, P3[t][0][p & 1]);
            const unsigned hi = bperm_u(srcl, P3[t][1][p & 1]);
            const unsigned m2 = bperm_u(srcl, P3[t][2][p & 1]);
            dk0[p] = (4 * g + p < 8) ? lo : hi;
            dk1[p] = (4 * g + p < 8) ? m2 : 0u;
        }
        if (g == 0) dk1[2] = (dk1[2] & 0xFFFF0000u) | 0x3F80u;
        const bf16x8 B0 = mk_frag(dk0[0], dk0[1], dk0[2], dk0[3]);
        const bf16x8 B1 = mk_frag(dk1[0], dk1[1], dk1[2], dk1[3]);
        f32x4 D = __builtin_amdgcn_mfma_f32_16x16x32_bf16(A4_0, B0, zf, 0, 0, 0);
        D = __builtin_amdgcn_mfma_f32_16x16x32_bf16(A4_1, B1, D, 0, 0, 0);
        vout[t] = D.x;
    }

    // redistribute: point p's value sits in lane (p&15) of tile (p>>4)
    const unsigned r0 = bperm_u((unsigned)c16, __float_as_uint(vout[0]));
    const unsigned r1 = bperm_u((unsigned)c16, __float_as_uint(vout[1]));
    const unsigned r2 = bperm_u((unsigned)c16, __float_as_uint(vout[2]));
    const unsigned r3 = bperm_u((unsigned)c16, __float_as_uint(vout[3]));
    const unsigned vr = (g < 2) ? ((g == 0) ? r0 : r1) : ((g == 2) ? r2 : r3);

    feat[i] = vr;                           // coalesced value stream
}

// Wave-local LDS ordering (colmax): drain this wave's DS ops.
__device__ __forceinline__ void lds_wave_fence() {
    asm volatile("s_waitcnt lgkmcnt(0)" ::: "memory");
}

// ---------------------------------------------------------------------------
// Kernel B v6 (R16-verbatim, passed): octant-mapped dedup colmax.
// 2200 blocks = 8 octants x 275 groups; wave y covers
// w = oct*8800 + (grp*4+y) + k*1100, k=0..7.
// ---------------------------------------------------------------------------
__global__ void __launch_bounds__(256) colmax_kernel(
    const int* __restrict__ tindex,
    const int* __restrict__ counts,
    const unsigned* __restrict__ list4,
    const unsigned* __restrict__ feat,
    float* __restrict__ out,
    int maxk)
{
    __shared__ unsigned rowwin[4][200];
    const int lane = threadIdx.x;        // 0..63
    const int y    = threadIdx.y;        // 0..3
    unsigned* tbl = rowwin[y];

    const bool empty = (tindex[0] == -1);

    if (blockIdx.x == 0 && lane == 0 && y == 0)
        out[W_DIM] = empty ? 0.0f : 1.0f;    // flag output

    tbl[lane]       = 0u;
    tbl[lane + 64]  = 0u;
    tbl[lane + 128] = 0u;
    if (lane < 8) tbl[lane + 192] = 0u;
    lds_wave_fence();

    const int oct = blockIdx.x & 7;
    const int grp = blockIdx.x >> 3;     // 0..274
    const int wbase = oct * OCT_W + grp * 4 + y;

#pragma unroll
    for (int k = 0; k < 8; ++k) {
        const int w = wbase + k * 1100;  // covers [oct*8800, oct*8800+8800)

        int c = 0;
        if (!empty) {
            c = counts[w];
            if (c > maxk) c = maxk;
        }

        unsigned e4 = 0u, fb = 0u;
        const bool have = (lane < c);
        float v = FILL_V;
        if (have) {
            e4 = list4[(size_t)w * maxk + lane];
            fb = feat[e4 >> 8];               // own point's value bits (L2)
            atomicMax(&tbl[e4 & 0xFFu], e4);  // native ds_max_u32
        }
        lds_wave_fence();
        if (have) {
            if (tbl[e4 & 0xFFu] == e4)        // unique keys -> one winner/row
                v = __uint_as_float(fb);
            tbl[e4 & 0xFFu] = 0u;
        }
        lds_wave_fence();

#pragma unroll
        for (int off = 32; off > 0; off >>= 1)
            v = fmaxf(v, __shfl_down(v, off, 64));

        if (lane == 0) out[w] = v;
    }
}

extern "C" void kernel_launch(void* const* d_in, const int* in_sizes, int n_in,
                              void* d_out, int out_size, void* d_ws, size_t ws_size,
                              hipStream_t stream) {
    const float* input  = (const float*)d_in[0];
    const int*   tindex = (const int*)d_in[1];   // int32 on device
    const float* w1 = (const float*)d_in[2];
    const float* b1 = (const float*)d_in[3];
    const float* w2 = (const float*)d_in[4];
    const float* b2 = (const float*)d_in[5];
    const float* w3 = (const float*)d_in[6];
    const float* b3 = (const float*)d_in[7];
    const float* w4 = (const float*)d_in[8];
    const float* b4 = (const float*)d_in[9];
    float* out = (float*)d_out;

    int*            counts = (int*)d_ws;
    unsigned short* wpack  = (unsigned short*)((char*)d_ws + COUNTS_BYTES);
    unsigned*       feat   = (unsigned*)((char*)d_ws + COUNTS_BYTES + WPACK_BYTES);
    unsigned*       list4  = (unsigned*)((char*)d_ws + COUNTS_BYTES + WPACK_BYTES + FEAT_BYTES);

    size_t head = COUNTS_BYTES + WPACK_BYTES + FEAT_BYTES;
    size_t avail = (ws_size > head) ? ws_size - head : 0;
    int maxk = (int)(avail / ((size_t)W_DIM * sizeof(unsigned)));
    if (maxk > 64) maxk = 64;
    if (maxk < 1)  maxk = 1;

    (void)hipMemsetAsync(counts, 0, COUNTS_BYTES, stream);

    pack_weights_kernel<<<1, 256, 0, stream>>>(w1, b1, w2, b2, w3, b3, w4, b4, wpack);

    // Fused work dispatch: slot blocks [0,2048) + mlp blocks [2048,5955).
    work_kernel<<<SLOT_BLKS + MLP_BLKS, 256, 0, stream>>>(
        input, tindex, wpack, counts, feat, list4, maxk);

    // Octant-partitioned colmax: 2200 = 8 octants x 275 groups.
    colmax_kernel<<<2200, dim3(64, 4), 0, stream>>>(
        tindex, counts, list4, feat, out, maxk);
}